// Round 3
// baseline (186.581 us; speedup 1.0000x reference)
//
#include <hip/hip_runtime.h>
#include <hip/hip_bf16.h>
#include <stdint.h>

typedef __hip_bfloat16 bf16;
typedef __attribute__((ext_vector_type(8))) __bf16 frag8;
typedef __attribute__((ext_vector_type(4))) float f32x4;

#define GLDS16(gsrc, ldst)                                                        \
  __builtin_amdgcn_global_load_lds(                                               \
      (const __attribute__((address_space(1))) void*)(gsrc),                      \
      (__attribute__((address_space(3))) void*)(ldst), 16, 0, 0)

// ---------------- helpers ----------------
__device__ inline float wred_sum(float v) {
#pragma unroll
  for (int o = 32; o; o >>= 1) v += __shfl_down(v, o);
  return v;
}
__device__ inline float wred_max(float v) {
#pragma unroll
  for (int o = 32; o; o >>= 1) v = fmaxf(v, __shfl_down(v, o));
  return v;
}
__device__ inline unsigned short bits_of(bf16 h) { return *(unsigned short*)&h; }

// ---------------- 0. bulk fp32 -> bf16 convert (weights + roi) ----------------
__global__ __launch_bounds__(256) void convert_all(
    const float* __restrict__ s0, bf16* __restrict__ d0, int n0,
    const float* __restrict__ s1, bf16* __restrict__ d1, int n1,
    const float* __restrict__ s2, bf16* __restrict__ d2, int n2,
    const float* __restrict__ s3, bf16* __restrict__ d3, int n3,
    const float* __restrict__ s4, bf16* __restrict__ d4, int n4) {
  int i = blockIdx.x * 256 + threadIdx.x;
  if (i < n0) { d0[i] = __float2bfloat16(s0[i]); return; } i -= n0;
  if (i < n1) { d1[i] = __float2bfloat16(s1[i]); return; } i -= n1;
  if (i < n2) { d2[i] = __float2bfloat16(s2[i]); return; } i -= n2;
  if (i < n3) { d3[i] = __float2bfloat16(s3[i]); return; } i -= n3;
  if (i < n4) { d4[i] = __float2bfloat16(s4[i]); }
}

// ---------------- 1. FUSED conv: img[b][o][p] = sum_c W[o][c] X[b][c][p] + bias[o]
// BM=256 (all o), BN=64 p, BK=32. 256 threads = 4 waves; wave w owns o = w*64..+63.
// Reg-staged double-buffered LDS, ONE barrier per K-step (T14 async-stage):
//   ds_write(t) -> issue loads(t+1) -> barrier -> ds_read+MFMA(t)
// Swizzle: byte ^= (row&7)<<4 on both write and read (A and B tiles).
__global__ __launch_bounds__(256) void conv_fused(
    const float* __restrict__ X, const bf16* __restrict__ W,
    const float* __restrict__ bias, bf16* __restrict__ img) {
  int b = blockIdx.y;
  int p0 = blockIdx.x * 64;
  __shared__ __align__(16) bf16 lA[2][256 * 32];   // 16 KB each, [o][c] 64B rows
  __shared__ __align__(16) bf16 lB[2][64 * 32];    // 4 KB each,  [p][c] 64B rows
  int tid = threadIdx.x, w = tid >> 6, lane = tid & 63;
  int lr = lane & 15, kg = lane >> 4;
  int aro = tid >> 2, aslot = tid & 3;     // A staging: row base, 16B slot
  int cpair = tid >> 4, pquad = tid & 15;  // B staging: c pair, p base
  const bool edge = (p0 + 64 > 1204);

  uint4 aR[4];
  float bR0[4], bR1[4];

  auto loadA = [&](int k0) {
#pragma unroll
    for (int q = 0; q < 4; ++q)
      aR[q] = *(const uint4*)((const char*)W + (long)(q * 64 + aro) * 1536 +
                              k0 * 2 + aslot * 16);
  };
  auto loadB = [&](int k0) {
    const float* xb = X + ((long)b * 768 + k0 + 2 * cpair) * 1204 + p0 + pquad;
    if (!edge) {
#pragma unroll
      for (int j = 0; j < 4; ++j) {
        bR0[j] = xb[16 * j];
        bR1[j] = xb[1204 + 16 * j];
      }
    } else {
#pragma unroll
      for (int j = 0; j < 4; ++j) {
        bool ok = (p0 + pquad + 16 * j) < 1204;
        bR0[j] = ok ? xb[16 * j] : 0.f;
        bR1[j] = ok ? xb[1204 + 16 * j] : 0.f;
      }
    }
  };
  auto stage = [&](int buf) {
    char* La = (char*)lA[buf];
    char* Lb = (char*)lB[buf];
#pragma unroll
    for (int q = 0; q < 4; ++q) {
      int o = q * 64 + aro;
      int byte = (o * 64 + aslot * 16) ^ ((o & 7) << 4);
      *(uint4*)(La + byte) = aR[q];
    }
#pragma unroll
    for (int j = 0; j < 4; ++j) {
      int p = pquad + 16 * j;
      unsigned pk = (unsigned)bits_of(__float2bfloat16(bR0[j])) |
                    ((unsigned)bits_of(__float2bfloat16(bR1[j])) << 16);
      int byte = (p * 64 + cpair * 4) ^ ((p & 7) << 4);
      *(unsigned*)(Lb + byte) = pk;
    }
  };

  f32x4 acc[4][4] = {};
  loadA(0);
  loadB(0);
  for (int t = 0; t < 24; ++t) {
    int buf = t & 1;
    stage(buf);
    if (t + 1 < 24) {
      loadA((t + 1) * 32);
      loadB((t + 1) * 32);
    }
    __syncthreads();
    const char* La = (const char*)lA[buf];
    const char* Lb = (const char*)lB[buf];
    frag8 af[4], bv[4];
#pragma unroll
    for (int mi = 0; mi < 4; ++mi) {
      int o = w * 64 + mi * 16 + lr;
      af[mi] = *(const frag8*)(La + ((o * 64 + kg * 16) ^ ((o & 7) << 4)));
    }
#pragma unroll
    for (int ni = 0; ni < 4; ++ni) {
      int p = ni * 16 + lr;
      bv[ni] = *(const frag8*)(Lb + ((p * 64 + kg * 16) ^ ((p & 7) << 4)));
    }
#pragma unroll
    for (int mi = 0; mi < 4; ++mi)
#pragma unroll
      for (int ni = 0; ni < 4; ++ni)
        acc[mi][ni] = __builtin_amdgcn_mfma_f32_16x16x32_bf16(af[mi], bv[ni],
                                                              acc[mi][ni], 0, 0, 0);
    __syncthreads();
  }
#pragma unroll
  for (int mi = 0; mi < 4; ++mi)
#pragma unroll
    for (int ni = 0; ni < 4; ++ni)
#pragma unroll
      for (int j = 0; j < 4; ++j) {
        int o = w * 64 + mi * 16 + kg * 4 + j;
        int p = p0 + ni * 16 + lr;   // pad cols (>=1204) land in img pitch pad: harmless
        float v = acc[mi][ni][j] + bias[o];
        img[((long)b * 256 + o) * 1280 + p] = __float2bfloat16(v);
      }
}

// ---------------- 2. small barrier-free GEMM: one wave per 64x64 tile ----------
// C[m][n] = sum_k A[m][k]*B[n][k] + bias[n]; M=384, N=256 (ldc=256).
template <bool RELU, bool OUT_BF16>
__global__ __launch_bounds__(64) void gemm_sm(const bf16* __restrict__ A,
                                              const bf16* __restrict__ B,
                                              void* __restrict__ C, int K,
                                              const float* __restrict__ bias) {
  int n0 = blockIdx.x * 64, m0 = blockIdx.y * 64;
  int lr = threadIdx.x & 15, kg = threadIdx.x >> 4;
  f32x4 acc[4][4] = {};
#pragma unroll 2
  for (int k0 = 0; k0 < K; k0 += 32) {
    frag8 af[4], bv[4];
#pragma unroll
    for (int mi = 0; mi < 4; ++mi)
      af[mi] = *(const frag8*)(A + (long)(m0 + mi * 16 + lr) * K + k0 + kg * 8);
#pragma unroll
    for (int ni = 0; ni < 4; ++ni)
      bv[ni] = *(const frag8*)(B + (long)(n0 + ni * 16 + lr) * K + k0 + kg * 8);
#pragma unroll
    for (int mi = 0; mi < 4; ++mi)
#pragma unroll
      for (int ni = 0; ni < 4; ++ni)
        acc[mi][ni] = __builtin_amdgcn_mfma_f32_16x16x32_bf16(af[mi], bv[ni],
                                                              acc[mi][ni], 0, 0, 0);
  }
#pragma unroll
  for (int mi = 0; mi < 4; ++mi)
#pragma unroll
    for (int ni = 0; ni < 4; ++ni)
#pragma unroll
      for (int j = 0; j < 4; ++j) {
        int row = m0 + mi * 16 + kg * 4 + j;
        int col = n0 + ni * 16 + lr;
        float v = acc[mi][ni][j] + bias[col];
        if (RELU) v = fmaxf(v, 0.f);
        long idx = (long)row * 256 + col;
        if constexpr (OUT_BF16) ((bf16*)C)[idx] = __float2bfloat16(v);
        else ((float*)C)[idx] = v;
      }
}

// ---------------- 3. logits[b][n][p] = sum_c emb[b][n][c] * img[b][c][p] -------
__global__ __launch_bounds__(256) void logits_k(const bf16* __restrict__ img,
                                                const float* __restrict__ emb,
                                                float* __restrict__ lgt) {
  int b = blockIdx.x;
  __shared__ float e[3072];
  const float* eb = emb + (long)b * 3072;
  for (int i = threadIdx.x; i < 3072; i += 256) e[i] = eb[i];
  __syncthreads();
  int p = blockIdx.y * 256 + threadIdx.x;
  if (p >= 1204) return;
  const bf16* ib = img + (long)b * 256 * 1280 + p;
  float acc[12] = {};
#pragma unroll 4
  for (int c = 0; c < 256; ++c) {
    float xv = __bfloat162float(ib[(long)c * 1280]);
#pragma unroll
    for (int n = 0; n < 12; ++n) acc[n] += e[n * 256 + c] * xv;
  }
#pragma unroll
  for (int n = 0; n < 12; ++n) lgt[((long)b * 12 + n) * 1204 + p] = acc[n];
}

// ---------------- 4. row softmax -> A_sm [32][16][1280] bf16 (zero padded) -----
__global__ __launch_bounds__(256) void softmax_k(const float* __restrict__ lgt,
                                                 bf16* __restrict__ am) {
  int b = blockIdx.x, n = blockIdx.y, tid = threadIdx.x;
  bf16* row = am + ((long)b * 16 + n) * 1280;
  if (n >= 12) {
    for (int i = tid; i < 1280; i += 256) row[i] = __float2bfloat16(0.f);
    return;
  }
  const float* lr = lgt + ((long)b * 12 + n) * 1204;
  float vals[5];
  float m = -3.0e38f;
#pragma unroll
  for (int i = 0; i < 5; ++i) {
    int pp = tid + i * 256;
    vals[i] = (pp < 1204) ? lr[pp] : -3.0e38f;
    m = fmaxf(m, vals[i]);
  }
  m = wred_max(m);
  __shared__ float rd[4];
  int w = tid >> 6, lane = tid & 63;
  if (lane == 0) rd[w] = m;
  __syncthreads();
  m = fmaxf(fmaxf(rd[0], rd[1]), fmaxf(rd[2], rd[3]));
  float s = 0.f;
#pragma unroll
  for (int i = 0; i < 5; ++i) {
    int pp = tid + i * 256;
    vals[i] = (pp < 1204) ? __expf(vals[i] - m) : 0.f;
    s += vals[i];
  }
  s = wred_sum(s);
  __syncthreads();
  if (lane == 0) rd[w] = s;
  __syncthreads();
  s = rd[0] + rd[1] + rd[2] + rd[3];
  float inv = 1.f / s;
#pragma unroll
  for (int i = 0; i < 5; ++i) {
    int pp = tid + i * 256;
    row[pp] = __float2bfloat16((pp < 1204) ? vals[i] * inv : 0.f);
  }
}

// ---------------- 5. ctx split-K: cpart[kc][b*12+n][c], K chunk = 256 ----------
__global__ __launch_bounds__(256) void ctx_split(const bf16* __restrict__ img,
                                                 const bf16* __restrict__ am,
                                                 float* __restrict__ cpart) {
  int b = blockIdx.x, kc = blockIdx.y;
  const bf16* Ab = img + (long)b * 256 * 1280;
  const bf16* Bb = am + (long)b * 16 * 1280;
  __shared__ __align__(16) bf16 lA[256 * 32];
  __shared__ __align__(16) bf16 lB[16 * 32];
  int tid = threadIdx.x, w = tid >> 6, lane = tid & 63;
  int lr = lane & 15, kg = lane >> 4;
  f32x4 acc[4] = {};
  int kend = kc * 256 + 256;
  for (int k0 = kc * 256; k0 < kend; k0 += 32) {
#pragma unroll
    for (int i = 0; i < 4; ++i) {
      int off = w * 4096 + i * 1024 + lane * 16;
      int row = off >> 6, kb = off & 63;
      GLDS16((const char*)Ab + (long)row * 2560 + k0 * 2 + kb,
             (char*)lA + w * 4096 + i * 1024);
    }
    if (w == 0) {
      int off = lane * 16, row = off >> 6, kb = off & 63;
      GLDS16((const char*)Bb + (long)row * 2560 + k0 * 2 + kb, (char*)lB);
    }
    __syncthreads();
    frag8 bv = *(const frag8*)((const char*)lB + lr * 64 + kg * 16);
#pragma unroll
    for (int mi = 0; mi < 4; ++mi) {
      frag8 av = *(const frag8*)((const char*)lA + (w * 64 + mi * 16 + lr) * 64 + kg * 16);
      acc[mi] = __builtin_amdgcn_mfma_f32_16x16x32_bf16(av, bv, acc[mi], 0, 0, 0);
    }
    __syncthreads();
  }
  int n = lr;
  if (n < 12) {
#pragma unroll
    for (int mi = 0; mi < 4; ++mi)
#pragma unroll
      for (int j = 0; j < 4; ++j)
        cpart[((long)kc * 384 + b * 12 + n) * 256 + (w * 64 + mi * 16 + kg * 4 + j)] =
            acc[mi][j];
  }
}

// ---------------- 6. LayerNorm over 256; a = sum of nparts slices + bb ---------
__global__ __launch_bounds__(256) void ln_k(const float* __restrict__ a, int nparts,
                                            long pstride, const float* __restrict__ bb,
                                            const float* __restrict__ g,
                                            const float* __restrict__ be,
                                            float* __restrict__ of,
                                            bf16* __restrict__ ob) {
  int r = blockIdx.x, c = threadIdx.x;
  long idx = (long)r * 256 + c;
  float v = bb[idx];
  for (int q = 0; q < nparts; ++q) v += a[idx + q * pstride];
  float s = wred_sum(v);
  float s2 = wred_sum(v * v);
  __shared__ float r1[4], r2[4];
  int w = c >> 6, lane = c & 63;
  if (lane == 0) { r1[w] = s; r2[w] = s2; }
  __syncthreads();
  float st = r1[0] + r1[1] + r1[2] + r1[3];
  float s2t = r2[0] + r2[1] + r2[2] + r2[3];
  float mean = st * (1.f / 256.f);
  float var = s2t * (1.f / 256.f) - mean * mean;
  float rs = rsqrtf(var + 1e-5f);
  float y = (v - mean) * rs * g[c] + be[c];
  if (of) of[idx] = y;
  if (ob) ob[idx] = __float2bfloat16(y);
}

// ---------------- launcher -----------------------------------------------------
extern "C" void kernel_launch(void* const* d_in, const int* in_sizes, int n_in,
                              void* d_out, int out_size, void* d_ws, size_t ws_size,
                              hipStream_t stream) {
  const float* roi   = (const float*)d_in[0];
  const float* imgf  = (const float*)d_in[1];
  const float* convw = (const float*)d_in[2];
  const float* convb = (const float*)d_in[3];
  const float* embw  = (const float*)d_in[4];
  const float* embb  = (const float*)d_in[5];
  const float* ln1g  = (const float*)d_in[6];
  const float* ln1b  = (const float*)d_in[7];
  const float* w1    = (const float*)d_in[8];
  const float* b1    = (const float*)d_in[9];
  const float* w2    = (const float*)d_in[10];
  const float* b2    = (const float*)d_in[11];
  const float* ln2g  = (const float*)d_in[12];
  const float* ln2b  = (const float*)d_in[13];
  float* out = (float*)d_out;

  char* p = (char*)d_ws;
  size_t off = 0;
  auto take = [&](size_t sz) -> char* {
    char* r = p + off;
    off += (sz + 255) & ~(size_t)255;
    return r;
  };
  bf16*  img   = (bf16*)take((size_t)32 * 256 * 1280 * 2);   // 21.0 MB
  bf16*  cwb   = (bf16*)take((size_t)256 * 768 * 2);
  bf16*  ewb   = (bf16*)take((size_t)256 * 1024 * 2);
  bf16*  w1b   = (bf16*)take((size_t)256 * 256 * 2);
  bf16*  w2b   = (bf16*)take((size_t)256 * 256 * 2);
  bf16*  roib  = (bf16*)take((size_t)384 * 1024 * 2);
  float* emb   = (float*)take((size_t)384 * 256 * 4);
  float* lgt   = (float*)take((size_t)384 * 1204 * 4);
  bf16*  am    = (bf16*)take((size_t)32 * 16 * 1280 * 2);
  float* cpart = (float*)take((size_t)5 * 384 * 256 * 4);
  float* x     = (float*)take((size_t)384 * 256 * 4);
  bf16*  xb    = (bf16*)take((size_t)384 * 256 * 2);
  bf16*  h1    = (bf16*)take((size_t)384 * 256 * 2);
  float* h     = (float*)take((size_t)384 * 256 * 4);

  // 0. converts (weights + roi)
  {
    int total = 196608 + 262144 + 65536 + 65536 + 393216;
    convert_all<<<(total + 255) / 256, 256, 0, stream>>>(
        convw, cwb, 196608, embw, ewb, 262144, w1, w1b, 65536, w2, w2b, 65536,
        roi, roib, 393216);
  }
  // 1. emb GEMM: emb[384][256] fp32 (barrier-free, 24 blocks)
  gemm_sm<false, false><<<dim3(4, 6), 64, 0, stream>>>(roib, ewb, emb, 1024, embb);
  // 2. fused transpose+convert+conv GEMM (pipelined reg-staging)
  conv_fused<<<dim3(19, 32), 256, 0, stream>>>(imgf, cwb, convb, img);
  // 3. logits
  logits_k<<<dim3(32, 5), 256, 0, stream>>>(img, emb, lgt);
  // 4. softmax -> A_sm (bf16, padded with zeros)
  softmax_k<<<dim3(32, 16), 256, 0, stream>>>(lgt, am);
  // 5. ctx split-K over 5 chunks of 256
  ctx_split<<<dim3(32, 5), 256, 0, stream>>>(img, am, cpart);
  // 6. LN1: x = LN(sum(cpart) + emb)
  ln_k<<<384, 256, 0, stream>>>(cpart, 5, (long)384 * 256, emb, ln1g, ln1b, x, xb);
  // 7/8. FFN
  gemm_sm<true, true><<<dim3(4, 6), 64, 0, stream>>>(xb, w1b, h1, 256, b1);
  gemm_sm<false, false><<<dim3(4, 6), 64, 0, stream>>>(h1, w2b, h, 256, b2);
  // 9. LN2 -> out
  ln_k<<<384, 256, 0, stream>>>(h, 1, 0, x, ln2g, ln2b, out, nullptr);
}

// Round 4
// 135.334 us; speedup vs baseline: 1.3787x; 1.3787x over previous
//
#include <hip/hip_runtime.h>
#include <hip/hip_bf16.h>
#include <stdint.h>

typedef __hip_bfloat16 bf16;
typedef __attribute__((ext_vector_type(8))) __bf16 frag8;
typedef __attribute__((ext_vector_type(4))) float f32x4;

#define GLDS16(gsrc, ldst)                                                        \
  __builtin_amdgcn_global_load_lds(                                               \
      (const __attribute__((address_space(1))) void*)(gsrc),                      \
      (__attribute__((address_space(3))) void*)(ldst), 16, 0, 0)

// ---------------- helpers ----------------
__device__ inline float wred_sum(float v) {
#pragma unroll
  for (int o = 32; o; o >>= 1) v += __shfl_down(v, o);
  return v;
}
__device__ inline float wred_max(float v) {
#pragma unroll
  for (int o = 32; o; o >>= 1) v = fmaxf(v, __shfl_down(v, o));
  return v;
}
__device__ inline unsigned short bits_of(bf16 h) { return *(unsigned short*)&h; }

// ---------------- 0. bulk fp32 -> bf16 convert (weights + roi) ----------------
__global__ __launch_bounds__(256) void convert_all(
    const float* __restrict__ s0, bf16* __restrict__ d0, int n0,
    const float* __restrict__ s1, bf16* __restrict__ d1, int n1,
    const float* __restrict__ s2, bf16* __restrict__ d2, int n2,
    const float* __restrict__ s3, bf16* __restrict__ d3, int n3,
    const float* __restrict__ s4, bf16* __restrict__ d4, int n4) {
  int i = blockIdx.x * 256 + threadIdx.x;
  if (i < n0) { d0[i] = __float2bfloat16(s0[i]); return; } i -= n0;
  if (i < n1) { d1[i] = __float2bfloat16(s1[i]); return; } i -= n1;
  if (i < n2) { d2[i] = __float2bfloat16(s2[i]); return; } i -= n2;
  if (i < n3) { d3[i] = __float2bfloat16(s3[i]); return; } i -= n3;
  if (i < n4) { d4[i] = __float2bfloat16(s4[i]); }
}

// ---------------- 1. FUSED conv: img[b][o][p] = sum_c W[o][c] X[b][c][p] + bias[o]
// BM=256 (all o), BN=64 p, BK=32; 256 threads = 4 waves, wave w owns o=w*64..+63.
// Reg-staged, double-buffered LDS, ONE barrier per K-step:
//   stage(t)->LDS[buf]; issue loads(t+1)->regs; barrier; ds_read+MFMA(buf).
// All staging state in named scalars (no arrays -> no scratch; rule #20).
// XOR swizzle byte ^= (row&7)<<4 on LDS write AND read (2-way residual = free).
__global__ __launch_bounds__(256, 2) void conv_fused(
    const float* __restrict__ X, const bf16* __restrict__ W,
    const float* __restrict__ bias, bf16* __restrict__ img) {
  int b = blockIdx.y;
  int p0 = blockIdx.x * 64;
  __shared__ __align__(16) bf16 lA[2][256 * 32];   // 16 KB each: [o][c], 64B rows
  __shared__ __align__(16) bf16 lB[2][64 * 32];    // 4 KB each:  [p][c], 64B rows
  int tid = threadIdx.x, w = tid >> 6, lane = tid & 63;
  int lr = lane & 15, kg = lane >> 4;
  int aro = tid >> 2, aslot = tid & 3;     // A staging: row aro(+64q), 16B slot
  int cpair = tid >> 4, pquad = tid & 15;  // B staging: c rows {2cpair,2cpair+1}, p = pquad+16j
  const bool edge = (p0 + 64 > 1204);

  const char* Wp = (const char*)W + (long)aro * 1536 + aslot * 16;
  const float* Xp = X + ((long)b * 768 + 2 * cpair) * 1204 + p0 + pquad;

  // staging registers (named scalars only)
  uint4 a0, a1, a2, a3;
  float c00, c01, c02, c03, c10, c11, c12, c13;

#define LOADK(k0)                                                                  \
  {                                                                                \
    const char* wp_ = Wp + (k0) * 2;                                               \
    a0 = *(const uint4*)(wp_);                                                     \
    a1 = *(const uint4*)(wp_ + (long)64 * 1536);                                   \
    a2 = *(const uint4*)(wp_ + (long)128 * 1536);                                  \
    a3 = *(const uint4*)(wp_ + (long)192 * 1536);                                  \
    const float* xp_ = Xp + (long)(k0) * 1204;                                     \
    if (!edge) {                                                                   \
      c00 = xp_[0];    c01 = xp_[16];   c02 = xp_[32];   c03 = xp_[48];            \
      c10 = xp_[1204]; c11 = xp_[1220]; c12 = xp_[1236]; c13 = xp_[1252];          \
    } else {                                                                       \
      bool k0_ = (p0 + pquad) < 1204, k1_ = (p0 + pquad + 16) < 1204;              \
      bool k2_ = (p0 + pquad + 32) < 1204, k3_ = (p0 + pquad + 48) < 1204;         \
      c00 = k0_ ? xp_[0] : 0.f;    c01 = k1_ ? xp_[16] : 0.f;                      \
      c02 = k2_ ? xp_[32] : 0.f;   c03 = k3_ ? xp_[48] : 0.f;                      \
      c10 = k0_ ? xp_[1204] : 0.f; c11 = k1_ ? xp_[1220] : 0.f;                    \
      c12 = k2_ ? xp_[1236] : 0.f; c13 = k3_ ? xp_[1252] : 0.f;                    \
    }                                                                              \
  }

#define PACK(x, y) ((unsigned)bits_of(__float2bfloat16(x)) |                       \
                    ((unsigned)bits_of(__float2bfloat16(y)) << 16))

#define STAGE(buf)                                                                 \
  {                                                                                \
    char* La_ = (char*)lA[buf];                                                    \
    char* Lb_ = (char*)lB[buf];                                                    \
    int sw_ = (aro & 7) << 4;                                                      \
    *(uint4*)(La_ + (((aro)*64 + aslot * 16) ^ sw_)) = a0;                         \
    *(uint4*)(La_ + (((64 + aro) * 64 + aslot * 16) ^ sw_)) = a1;                  \
    *(uint4*)(La_ + (((128 + aro) * 64 + aslot * 16) ^ sw_)) = a2;                 \
    *(uint4*)(La_ + (((192 + aro) * 64 + aslot * 16) ^ sw_)) = a3;                 \
    int p_ = pquad;                                                                \
    *(unsigned*)(Lb_ + ((p_ * 64 + cpair * 4) ^ ((p_ & 7) << 4))) = PACK(c00, c10);\
    p_ = pquad + 16;                                                               \
    *(unsigned*)(Lb_ + ((p_ * 64 + cpair * 4) ^ ((p_ & 7) << 4))) = PACK(c01, c11);\
    p_ = pquad + 32;                                                               \
    *(unsigned*)(Lb_ + ((p_ * 64 + cpair * 4) ^ ((p_ & 7) << 4))) = PACK(c02, c12);\
    p_ = pquad + 48;                                                               \
    *(unsigned*)(Lb_ + ((p_ * 64 + cpair * 4) ^ ((p_ & 7) << 4))) = PACK(c03, c13);\
  }

  f32x4 acc[4][4] = {};
  LOADK(0);
#pragma unroll 2
  for (int t = 0; t < 24; ++t) {
    int buf = t & 1;
    STAGE(buf);
    if (t < 23) LOADK((t + 1) * 32);
    __syncthreads();
    const char* La = (const char*)lA[buf];
    const char* Lb = (const char*)lB[buf];
    frag8 af[4], bv[4];
#pragma unroll
    for (int mi = 0; mi < 4; ++mi) {
      int o = w * 64 + mi * 16 + lr;
      af[mi] = *(const frag8*)(La + ((o * 64 + kg * 16) ^ ((o & 7) << 4)));
    }
#pragma unroll
    for (int ni = 0; ni < 4; ++ni) {
      int p = ni * 16 + lr;
      bv[ni] = *(const frag8*)(Lb + ((p * 64 + kg * 16) ^ ((p & 7) << 4)));
    }
#pragma unroll
    for (int mi = 0; mi < 4; ++mi)
#pragma unroll
      for (int ni = 0; ni < 4; ++ni)
        acc[mi][ni] = __builtin_amdgcn_mfma_f32_16x16x32_bf16(af[mi], bv[ni],
                                                              acc[mi][ni], 0, 0, 0);
  }
#undef LOADK
#undef PACK
#undef STAGE
#pragma unroll
  for (int mi = 0; mi < 4; ++mi)
#pragma unroll
    for (int ni = 0; ni < 4; ++ni)
#pragma unroll
      for (int j = 0; j < 4; ++j) {
        int o = w * 64 + mi * 16 + kg * 4 + j;
        int p = p0 + ni * 16 + lr;   // p>=1204 lands in pitch pad: harmless
        float v = acc[mi][ni][j] + bias[o];
        img[((long)b * 256 + o) * 1280 + p] = __float2bfloat16(v);
      }
}

// ---------------- 2. small barrier-free GEMM: one wave per 64x64 tile ----------
template <bool RELU, bool OUT_BF16>
__global__ __launch_bounds__(64) void gemm_sm(const bf16* __restrict__ A,
                                              const bf16* __restrict__ B,
                                              void* __restrict__ C, int K,
                                              const float* __restrict__ bias) {
  int n0 = blockIdx.x * 64, m0 = blockIdx.y * 64;
  int lr = threadIdx.x & 15, kg = threadIdx.x >> 4;
  f32x4 acc[4][4] = {};
#pragma unroll 2
  for (int k0 = 0; k0 < K; k0 += 32) {
    frag8 af[4], bv[4];
#pragma unroll
    for (int mi = 0; mi < 4; ++mi)
      af[mi] = *(const frag8*)(A + (long)(m0 + mi * 16 + lr) * K + k0 + kg * 8);
#pragma unroll
    for (int ni = 0; ni < 4; ++ni)
      bv[ni] = *(const frag8*)(B + (long)(n0 + ni * 16 + lr) * K + k0 + kg * 8);
#pragma unroll
    for (int mi = 0; mi < 4; ++mi)
#pragma unroll
      for (int ni = 0; ni < 4; ++ni)
        acc[mi][ni] = __builtin_amdgcn_mfma_f32_16x16x32_bf16(af[mi], bv[ni],
                                                              acc[mi][ni], 0, 0, 0);
  }
#pragma unroll
  for (int mi = 0; mi < 4; ++mi)
#pragma unroll
    for (int ni = 0; ni < 4; ++ni)
#pragma unroll
      for (int j = 0; j < 4; ++j) {
        int row = m0 + mi * 16 + kg * 4 + j;
        int col = n0 + ni * 16 + lr;
        float v = acc[mi][ni][j] + bias[col];
        if (RELU) v = fmaxf(v, 0.f);
        long idx = (long)row * 256 + col;
        if constexpr (OUT_BF16) ((bf16*)C)[idx] = __float2bfloat16(v);
        else ((float*)C)[idx] = v;
      }
}

// ---------------- 3. logits[b][n][p] = sum_c emb[b][n][c] * img[b][c][p] -------
__global__ __launch_bounds__(256) void logits_k(const bf16* __restrict__ img,
                                                const float* __restrict__ emb,
                                                float* __restrict__ lgt) {
  int b = blockIdx.x;
  __shared__ float e[3072];
  const float* eb = emb + (long)b * 3072;
  for (int i = threadIdx.x; i < 3072; i += 256) e[i] = eb[i];
  __syncthreads();
  int p = blockIdx.y * 256 + threadIdx.x;
  if (p >= 1204) return;
  const bf16* ib = img + (long)b * 256 * 1280 + p;
  float acc[12] = {};
#pragma unroll 4
  for (int c = 0; c < 256; ++c) {
    float xv = __bfloat162float(ib[(long)c * 1280]);
#pragma unroll
    for (int n = 0; n < 12; ++n) acc[n] += e[n * 256 + c] * xv;
  }
#pragma unroll
  for (int n = 0; n < 12; ++n) lgt[((long)b * 12 + n) * 1204 + p] = acc[n];
}

// ---------------- 4. row softmax -> A_sm [32][16][1280] bf16 (zero padded) -----
__global__ __launch_bounds__(256) void softmax_k(const float* __restrict__ lgt,
                                                 bf16* __restrict__ am) {
  int b = blockIdx.x, n = blockIdx.y, tid = threadIdx.x;
  bf16* row = am + ((long)b * 16 + n) * 1280;
  if (n >= 12) {
    for (int i = tid; i < 1280; i += 256) row[i] = __float2bfloat16(0.f);
    return;
  }
  const float* lr = lgt + ((long)b * 12 + n) * 1204;
  float vals[5];
  float m = -3.0e38f;
#pragma unroll
  for (int i = 0; i < 5; ++i) {
    int pp = tid + i * 256;
    vals[i] = (pp < 1204) ? lr[pp] : -3.0e38f;
    m = fmaxf(m, vals[i]);
  }
  m = wred_max(m);
  __shared__ float rd[4];
  int w = tid >> 6, lane = tid & 63;
  if (lane == 0) rd[w] = m;
  __syncthreads();
  m = fmaxf(fmaxf(rd[0], rd[1]), fmaxf(rd[2], rd[3]));
  float s = 0.f;
#pragma unroll
  for (int i = 0; i < 5; ++i) {
    int pp = tid + i * 256;
    vals[i] = (pp < 1204) ? __expf(vals[i] - m) : 0.f;
    s += vals[i];
  }
  s = wred_sum(s);
  __syncthreads();
  if (lane == 0) rd[w] = s;
  __syncthreads();
  s = rd[0] + rd[1] + rd[2] + rd[3];
  float inv = 1.f / s;
#pragma unroll
  for (int i = 0; i < 5; ++i) {
    int pp = tid + i * 256;
    row[pp] = __float2bfloat16((pp < 1204) ? vals[i] * inv : 0.f);
  }
}

// ---------------- 5. ctx split-K: cpart[kc][b*12+n][c], K chunk = 256 ----------
__global__ __launch_bounds__(256) void ctx_split(const bf16* __restrict__ img,
                                                 const bf16* __restrict__ am,
                                                 float* __restrict__ cpart) {
  int b = blockIdx.x, kc = blockIdx.y;
  const bf16* Ab = img + (long)b * 256 * 1280;
  const bf16* Bb = am + (long)b * 16 * 1280;
  __shared__ __align__(16) bf16 lA[256 * 32];
  __shared__ __align__(16) bf16 lB[16 * 32];
  int tid = threadIdx.x, w = tid >> 6, lane = tid & 63;
  int lr = lane & 15, kg = lane >> 4;
  f32x4 acc[4] = {};
  int kend = kc * 256 + 256;
  for (int k0 = kc * 256; k0 < kend; k0 += 32) {
#pragma unroll
    for (int i = 0; i < 4; ++i) {
      int off = w * 4096 + i * 1024 + lane * 16;
      int row = off >> 6, kb = off & 63;
      GLDS16((const char*)Ab + (long)row * 2560 + k0 * 2 + kb,
             (char*)lA + w * 4096 + i * 1024);
    }
    if (w == 0) {
      int off = lane * 16, row = off >> 6, kb = off & 63;
      GLDS16((const char*)Bb + (long)row * 2560 + k0 * 2 + kb, (char*)lB);
    }
    __syncthreads();
    frag8 bv = *(const frag8*)((const char*)lB + lr * 64 + kg * 16);
#pragma unroll
    for (int mi = 0; mi < 4; ++mi) {
      frag8 av = *(const frag8*)((const char*)lA + (w * 64 + mi * 16 + lr) * 64 + kg * 16);
      acc[mi] = __builtin_amdgcn_mfma_f32_16x16x32_bf16(av, bv, acc[mi], 0, 0, 0);
    }
    __syncthreads();
  }
  int n = lr;
  if (n < 12) {
#pragma unroll
    for (int mi = 0; mi < 4; ++mi)
#pragma unroll
      for (int j = 0; j < 4; ++j)
        cpart[((long)kc * 384 + b * 12 + n) * 256 + (w * 64 + mi * 16 + kg * 4 + j)] =
            acc[mi][j];
  }
}

// ---------------- 6. LayerNorm over 256; a = sum of nparts slices + bb ---------
__global__ __launch_bounds__(256) void ln_k(const float* __restrict__ a, int nparts,
                                            long pstride, const float* __restrict__ bb,
                                            const float* __restrict__ g,
                                            const float* __restrict__ be,
                                            float* __restrict__ of,
                                            bf16* __restrict__ ob) {
  int r = blockIdx.x, c = threadIdx.x;
  long idx = (long)r * 256 + c;
  float v = bb[idx];
  for (int q = 0; q < nparts; ++q) v += a[idx + q * pstride];
  float s = wred_sum(v);
  float s2 = wred_sum(v * v);
  __shared__ float r1[4], r2[4];
  int w = c >> 6, lane = c & 63;
  if (lane == 0) { r1[w] = s; r2[w] = s2; }
  __syncthreads();
  float st = r1[0] + r1[1] + r1[2] + r1[3];
  float s2t = r2[0] + r2[1] + r2[2] + r2[3];
  float mean = st * (1.f / 256.f);
  float var = s2t * (1.f / 256.f) - mean * mean;
  float rs = rsqrtf(var + 1e-5f);
  float y = (v - mean) * rs * g[c] + be[c];
  if (of) of[idx] = y;
  if (ob) ob[idx] = __float2bfloat16(y);
}

// ---------------- launcher -----------------------------------------------------
extern "C" void kernel_launch(void* const* d_in, const int* in_sizes, int n_in,
                              void* d_out, int out_size, void* d_ws, size_t ws_size,
                              hipStream_t stream) {
  const float* roi   = (const float*)d_in[0];
  const float* imgf  = (const float*)d_in[1];
  const float* convw = (const float*)d_in[2];
  const float* convb = (const float*)d_in[3];
  const float* embw  = (const float*)d_in[4];
  const float* embb  = (const float*)d_in[5];
  const float* ln1g  = (const float*)d_in[6];
  const float* ln1b  = (const float*)d_in[7];
  const float* w1    = (const float*)d_in[8];
  const float* b1    = (const float*)d_in[9];
  const float* w2    = (const float*)d_in[10];
  const float* b2    = (const float*)d_in[11];
  const float* ln2g  = (const float*)d_in[12];
  const float* ln2b  = (const float*)d_in[13];
  float* out = (float*)d_out;

  char* p = (char*)d_ws;
  size_t off = 0;
  auto take = [&](size_t sz) -> char* {
    char* r = p + off;
    off += (sz + 255) & ~(size_t)255;
    return r;
  };
  bf16*  img   = (bf16*)take((size_t)32 * 256 * 1280 * 2);   // 21.0 MB
  bf16*  cwb   = (bf16*)take((size_t)256 * 768 * 2);
  bf16*  ewb   = (bf16*)take((size_t)256 * 1024 * 2);
  bf16*  w1b   = (bf16*)take((size_t)256 * 256 * 2);
  bf16*  w2b   = (bf16*)take((size_t)256 * 256 * 2);
  bf16*  roib  = (bf16*)take((size_t)384 * 1024 * 2);
  float* emb   = (float*)take((size_t)384 * 256 * 4);
  float* lgt   = (float*)take((size_t)384 * 1204 * 4);
  bf16*  am    = (bf16*)take((size_t)32 * 16 * 1280 * 2);
  float* cpart = (float*)take((size_t)5 * 384 * 256 * 4);
  float* x     = (float*)take((size_t)384 * 256 * 4);
  bf16*  xb    = (bf16*)take((size_t)384 * 256 * 2);
  bf16*  h1    = (bf16*)take((size_t)384 * 256 * 2);
  float* h     = (float*)take((size_t)384 * 256 * 4);

  // 0. converts (weights + roi)
  {
    int total = 196608 + 262144 + 65536 + 65536 + 393216;
    convert_all<<<(total + 255) / 256, 256, 0, stream>>>(
        convw, cwb, 196608, embw, ewb, 262144, w1, w1b, 65536, w2, w2b, 65536,
        roi, roib, 393216);
  }
  // 1. emb GEMM: emb[384][256] fp32 (barrier-free, 24 blocks)
  gemm_sm<false, false><<<dim3(4, 6), 64, 0, stream>>>(roib, ewb, emb, 1024, embb);
  // 2. fused transpose+convert+conv GEMM (pipelined reg-staging, no spills)
  conv_fused<<<dim3(19, 32), 256, 0, stream>>>(imgf, cwb, convb, img);
  // 3. logits
  logits_k<<<dim3(32, 5), 256, 0, stream>>>(img, emb, lgt);
  // 4. softmax -> A_sm (bf16, padded with zeros)
  softmax_k<<<dim3(32, 16), 256, 0, stream>>>(lgt, am);
  // 5. ctx split-K over 5 chunks of 256
  ctx_split<<<dim3(32, 5), 256, 0, stream>>>(img, am, cpart);
  // 6. LN1: x = LN(sum(cpart) + emb)
  ln_k<<<384, 256, 0, stream>>>(cpart, 5, (long)384 * 256, emb, ln1g, ln1b, x, xb);
  // 7/8. FFN
  gemm_sm<true, true><<<dim3(4, 6), 64, 0, stream>>>(xb, w1b, h1, 256, b1);
  gemm_sm<false, false><<<dim3(4, 6), 64, 0, stream>>>(h1, w2b, h, 256, b2);
  // 9. LN2 -> out
  ln_k<<<384, 256, 0, stream>>>(h, 1, 0, x, ln2g, ln2b, out, nullptr);
}